// Round 1
// baseline (638.629 us; speedup 1.0000x reference)
//
#include <hip/hip_runtime.h>

#define B_ 4
#define N_ 2048
#define D_ 2048

#define BM 128
#define BN 128
#define BK 32

typedef __bf16 bf16x8 __attribute__((ext_vector_type(8)));
typedef float  f32x4  __attribute__((ext_vector_type(4)));

__device__ __forceinline__ ushort f2bf(float x) {
  union { float f; unsigned u; } c; c.f = x;
  unsigned u = c.u;
  u += 0x7fffu + ((u >> 16) & 1u);   // RNE
  return (ushort)(u >> 16);
}

// async global->LDS, 16B per lane; lds base must be wave-uniform (HW adds lane*16)
__device__ __forceinline__ void gld16(ushort* lds, const ushort* g) {
  __builtin_amdgcn_global_load_lds(
      (const __attribute__((address_space(1))) void*)g,
      (__attribute__((address_space(3))) void*)lds, 16, 0, 0);
}

// ---------------- prep kernels ----------------

// one block per row: cn = bf16(data * rsqrt(max(sum(data^2),eps))), catA[:, :D] = bf16(data)
__global__ void prep_cn(const float* __restrict__ data, ushort* __restrict__ cn,
                        ushort* __restrict__ catA) {
  const int row = blockIdx.x;                 // 0..B*N-1
  const long base = (long)row * D_;
  const float4* r4 = (const float4*)(data + base);
  const int tid = threadIdx.x;                // 256 threads, 8 floats each
  float4 u0 = r4[tid * 2], u1 = r4[tid * 2 + 1];
  float s = u0.x*u0.x + u0.y*u0.y + u0.z*u0.z + u0.w*u0.w
          + u1.x*u1.x + u1.y*u1.y + u1.z*u1.z + u1.w*u1.w;
  #pragma unroll
  for (int o = 32; o > 0; o >>= 1) s += __shfl_down(s, o);
  __shared__ float wsum[4];
  if ((tid & 63) == 0) wsum[tid >> 6] = s;
  __syncthreads();
  const float tot = wsum[0] + wsum[1] + wsum[2] + wsum[3];
  const float sc = rsqrtf(fmaxf(tot, 1e-12f));
  uint4 pc, pd;
  pc.x = (unsigned)f2bf(u0.x * sc) | ((unsigned)f2bf(u0.y * sc) << 16);
  pc.y = (unsigned)f2bf(u0.z * sc) | ((unsigned)f2bf(u0.w * sc) << 16);
  pc.z = (unsigned)f2bf(u1.x * sc) | ((unsigned)f2bf(u1.y * sc) << 16);
  pc.w = (unsigned)f2bf(u1.z * sc) | ((unsigned)f2bf(u1.w * sc) << 16);
  pd.x = (unsigned)f2bf(u0.x) | ((unsigned)f2bf(u0.y) << 16);
  pd.y = (unsigned)f2bf(u0.z) | ((unsigned)f2bf(u0.w) << 16);
  pd.z = (unsigned)f2bf(u1.x) | ((unsigned)f2bf(u1.y) << 16);
  pd.w = (unsigned)f2bf(u1.z) | ((unsigned)f2bf(u1.w) << 16);
  *(uint4*)(cn + base + tid * 8) = pc;
  *(uint4*)(catA + (long)row * (2 * D_) + tid * 8) = pd;
}

// sinusoidal posenc [N][D] in bf16
__global__ void prep_pe(ushort* __restrict__ pe) {
  const int id = blockIdx.x * 256 + threadIdx.x;
  const int n = id >> 11, d = id & (D_ - 1);
  const double e = (double)(2 * (d >> 1)) / (double)D_;
  const double rate = exp(e * -9.210340371976184);   // 10000^-e
  const double ang = (double)n * rate;
  const float v = (d & 1) ? (float)cos(ang) : (float)sin(ang);
  pe[id] = f2bf(v);
}

// out[c][r] = bf16(in[r][c]); in is [R][C] fp32
__global__ void transpose_bf16(const float* __restrict__ in, ushort* __restrict__ out,
                               int R, int C) {
  __shared__ float t[32][33];
  const int c0 = blockIdx.x * 32, r0 = blockIdx.y * 32;
  const int tx = threadIdx.x, ty = threadIdx.y;   // (32,8)
  #pragma unroll
  for (int i = 0; i < 32; i += 8) t[ty + i][tx] = in[(long)(r0 + ty + i) * C + c0 + tx];
  __syncthreads();
  #pragma unroll
  for (int i = 0; i < 32; i += 8) out[(long)(c0 + ty + i) * R + r0 + tx] = f2bf(t[tx][ty + i]);
}

// ---------------- NT GEMM: C[m][n] = sum_k A[m][k]*B[n][k]  (m97 structure) ----------------
// MODE 0: sim = relu(acc) -> bf16, atomicAdd row sums into csum
// MODE 1: bf16 store
// MODE 2: softplus(acc + csum[row]*w0[col] + bexp[col]) -> bf16 at col+colOff
// MODE 3: fp32 store
template <int MODE>
__global__ __launch_bounds__(256, 2) void gemm_bt(
    const ushort* __restrict__ Ag, const ushort* __restrict__ Bg, void* __restrict__ Cg,
    int K, long sA, long sB, long sC, int ldc, int colOff,
    float* __restrict__ csum, const float* __restrict__ w0, const float* __restrict__ bexp) {
  __shared__ ushort sAt[BM * BK];   // [row][k], 64B rows
  __shared__ ushort sBt[BN * BK];   // [col][k]

  const int bz = blockIdx.z;
  const ushort* A  = Ag + (long)bz * sA;
  const ushort* Bp = Bg + (long)bz * sB;

  const int tid = threadIdx.x;
  const int w = tid >> 6, L = tid & 63;
  const int blockRow = blockIdx.x * BM;
  const int blockCol = blockIdx.y * BN;

  // staging: lane L of wave w covers row w*16+L/4 (+64 for round 1), k-chunk (L%4)*8
  const int ldRow = w * 16 + (L >> 2);
  const int ldK = (L & 3) * 8;
  const ushort* a0 = A  + (long)(blockRow + ldRow) * K + ldK;
  const ushort* a1 = a0 + (long)64 * K;
  const ushort* b0 = Bp + (long)(blockCol + ldRow) * K + ldK;
  const ushort* b1 = b0 + (long)64 * K;
  ushort* sA0 = sAt + w * 512;
  ushort* sA1 = sAt + 2048 + w * 512;
  ushort* sB0 = sBt + w * 512;
  ushort* sB1 = sBt + 2048 + w * 512;

  const int wm = (w & 1) * 64, wn = (w >> 1) * 64;   // wave's 64x64 quadrant
  const int fr = L & 15, fk = (L >> 4) * 8;          // fragment row / k-offset

  f32x4 acc[4][4] = {};

  for (int k0 = 0; k0 < K; k0 += BK) {
    gld16(sA0, a0); gld16(sA1, a1);
    gld16(sB0, b0); gld16(sB1, b1);
    a0 += BK; a1 += BK; b0 += BK; b1 += BK;
    __syncthreads();                               // staging complete (vmcnt drained)
    bf16x8 af[4], bfv[4];
    #pragma unroll
    for (int i = 0; i < 4; i++) af[i]  = *(const bf16x8*)&sAt[(wm + i * 16 + fr) * BK + fk];
    #pragma unroll
    for (int j = 0; j < 4; j++) bfv[j] = *(const bf16x8*)&sBt[(wn + j * 16 + fr) * BK + fk];
    #pragma unroll
    for (int i = 0; i < 4; i++)
      #pragma unroll
      for (int j = 0; j < 4; j++)
        acc[i][j] = __builtin_amdgcn_mfma_f32_16x16x32_bf16(af[i], bfv[j], acc[i][j], 0, 0, 0);
    __syncthreads();                               // reads done before next-iter overwrite
  }

  const int rq = (L >> 4) * 4;   // C/D: row = rq + reg, col = L&15 (m89-verified)
  const int cq = L & 15;

  if (MODE == 0) {
    ushort* C = (ushort*)Cg + (long)bz * sC;
    float rs[4][4];
    #pragma unroll
    for (int i = 0; i < 4; i++)
      #pragma unroll
      for (int r = 0; r < 4; r++) rs[i][r] = 0.f;
    #pragma unroll
    for (int i = 0; i < 4; i++)
      #pragma unroll
      for (int j = 0; j < 4; j++)
        #pragma unroll
        for (int r = 0; r < 4; r++) {
          const float v = fmaxf(acc[i][j][r], 0.f);
          const int row = blockRow + wm + i * 16 + rq + r;
          const int col = blockCol + wn + j * 16 + cq;
          C[(long)row * ldc + col] = f2bf(v);
          rs[i][r] += v;
        }
    #pragma unroll
    for (int i = 0; i < 4; i++)
      #pragma unroll
      for (int r = 0; r < 4; r++) {
        float s = rs[i][r];
        s += __shfl_xor(s, 1); s += __shfl_xor(s, 2);
        s += __shfl_xor(s, 4); s += __shfl_xor(s, 8);
        if (cq == 0) {
          const int row = blockRow + wm + i * 16 + rq + r;
          atomicAdd(&csum[(long)bz * N_ + row], s);
        }
      }
  } else if (MODE == 1) {
    ushort* C = (ushort*)Cg + (long)bz * sC;
    #pragma unroll
    for (int i = 0; i < 4; i++)
      #pragma unroll
      for (int j = 0; j < 4; j++)
        #pragma unroll
        for (int r = 0; r < 4; r++) {
          const int row = blockRow + wm + i * 16 + rq + r;
          const int col = blockCol + wn + j * 16 + cq;
          C[(long)row * ldc + col] = f2bf(acc[i][j][r]);
        }
  } else if (MODE == 2) {
    ushort* C = (ushort*)Cg + (long)bz * sC;
    #pragma unroll
    for (int i = 0; i < 4; i++)
      #pragma unroll
      for (int j = 0; j < 4; j++)
        #pragma unroll
        for (int r = 0; r < 4; r++) {
          const int row = blockRow + wm + i * 16 + rq + r;
          const int col = blockCol + wn + j * 16 + cq;
          const float x = acc[i][j][r] + csum[(long)bz * N_ + row] * w0[col] + bexp[col];
          const float sp = fmaxf(x, 0.f) + log1pf(expf(-fabsf(x)));
          C[(long)row * ldc + colOff + col] = f2bf(sp);
        }
  } else {
    float* C = (float*)Cg + (long)bz * sC;
    #pragma unroll
    for (int i = 0; i < 4; i++)
      #pragma unroll
      for (int j = 0; j < 4; j++)
        #pragma unroll
        for (int r = 0; r < 4; r++) {
          const int row = blockRow + wm + i * 16 + rq + r;
          const int col = blockCol + wn + j * 16 + cq;
          C[(long)row * ldc + col] = acc[i][j][r];
        }
  }
}

// ---------------- launch ----------------
extern "C" void kernel_launch(void* const* d_in, const int* in_sizes, int n_in,
                              void* d_out, int out_size, void* d_ws, size_t ws_size,
                              hipStream_t stream) {
  const float* data    = (const float*)d_in[0];
  const float* W_exp   = (const float*)d_in[1];
  const float* b_exp   = (const float*)d_in[2];
  const float* W_merge = (const float*)d_in[3];

  char* ws = (char*)d_ws;
  const size_t MB = 1024 * 1024;
  ushort* cnv  = (ushort*)(ws);             // 32MB: cn, then reused as v_out
  ushort* sim  = (ushort*)(ws + 32 * MB);   // 32MB
  ushort* pe   = (ushort*)(ws + 64 * MB);   // 8MB
  ushort* weT  = (ushort*)(ws + 72 * MB);   // 8MB:  W_exp[1:,:]^T
  ushort* wmT  = (ushort*)(ws + 80 * MB);   // 16MB: W_merge^T
  ushort* catA = (ushort*)(ws + 96 * MB);   // 64MB: [data | counter] bf16
  float*  csum = (float*)(ws + 160 * MB);   // 128KB

  hipMemsetAsync(csum, 0, (size_t)B_ * N_ * sizeof(float), stream);
  prep_cn<<<B_ * N_, 256, 0, stream>>>(data, cnv, catA);
  prep_pe<<<(N_ * N_) / 256, 256, 0, stream>>>(pe);
  transpose_bf16<<<dim3(D_ / 32, D_ / 32), dim3(32, 8), 0, stream>>>(W_exp + D_, weT, D_, D_);
  transpose_bf16<<<dim3(D_ / 32, (2 * D_) / 32), dim3(32, 8), 0, stream>>>(W_merge, wmT, 2 * D_, D_);

  dim3 g(N_ / BM, N_ / BN, B_), blk(256);
  // G1: sim = relu(cn cn^T), csum row sums
  gemm_bt<0><<<g, blk, 0, stream>>>(cnv, cnv, sim, D_, (long)N_ * D_, (long)N_ * D_,
                                    (long)N_ * N_, N_, 0, csum, nullptr, nullptr);
  // G2: v_out = pe @ sim  (sim symmetric -> NT form), into cnv region (cn is dead)
  gemm_bt<1><<<g, blk, 0, stream>>>(pe, sim, cnv, N_, 0, (long)N_ * N_,
                                    (long)N_ * N_, N_, 0, nullptr, nullptr, nullptr);
  // G3: catA[:, D:] = softplus(v_out @ W_exp[1:] + csum*w0 + b_exp)
  gemm_bt<2><<<g, blk, 0, stream>>>(cnv, weT, catA, N_, (long)N_ * N_, 0,
                                    (long)N_ * 2 * D_, 2 * D_, D_, csum, W_exp, b_exp);
  // G4: out = catA @ W_merge
  gemm_bt<3><<<g, blk, 0, stream>>>(catA, wmT, d_out, 2 * D_, (long)N_ * 2 * D_, 0,
                                    (long)N_ * D_, D_, 0, nullptr, nullptr, nullptr);
}

// Round 2
// 614.539 us; speedup vs baseline: 1.0392x; 1.0392x over previous
//
#include <hip/hip_runtime.h>

#define B_ 4
#define N_ 2048
#define D_ 2048

#define BM 128
#define BN 128
#define BK 32

typedef __bf16 bf16x8 __attribute__((ext_vector_type(8)));
typedef float  f32x4  __attribute__((ext_vector_type(4)));

__device__ __forceinline__ ushort f2bf(float x) {
  union { float f; unsigned u; } c; c.f = x;
  unsigned u = c.u;
  u += 0x7fffu + ((u >> 16) & 1u);   // RNE
  return (ushort)(u >> 16);
}

// async global->LDS, 16B per lane; lds base must be wave-uniform (HW adds lane*16)
__device__ __forceinline__ void gld16(ushort* lds, const ushort* g) {
  __builtin_amdgcn_global_load_lds(
      (const __attribute__((address_space(1))) void*)g,
      (__attribute__((address_space(3))) void*)lds, 16, 0, 0);
}

// ---------------- prep kernels ----------------

// one block per row: cn = bf16(data * rsqrt(max(sum(data^2),eps))), catA[:, :D] = bf16(data)
__global__ void prep_cn(const float* __restrict__ data, ushort* __restrict__ cn,
                        ushort* __restrict__ catA) {
  const int row = blockIdx.x;                 // 0..B*N-1
  const long base = (long)row * D_;
  const float4* r4 = (const float4*)(data + base);
  const int tid = threadIdx.x;                // 256 threads, 8 floats each
  float4 u0 = r4[tid * 2], u1 = r4[tid * 2 + 1];
  float s = u0.x*u0.x + u0.y*u0.y + u0.z*u0.z + u0.w*u0.w
          + u1.x*u1.x + u1.y*u1.y + u1.z*u1.z + u1.w*u1.w;
  #pragma unroll
  for (int o = 32; o > 0; o >>= 1) s += __shfl_down(s, o);
  __shared__ float wsum[4];
  if ((tid & 63) == 0) wsum[tid >> 6] = s;
  __syncthreads();
  const float tot = wsum[0] + wsum[1] + wsum[2] + wsum[3];
  const float sc = rsqrtf(fmaxf(tot, 1e-12f));
  uint4 pc, pd;
  pc.x = (unsigned)f2bf(u0.x * sc) | ((unsigned)f2bf(u0.y * sc) << 16);
  pc.y = (unsigned)f2bf(u0.z * sc) | ((unsigned)f2bf(u0.w * sc) << 16);
  pc.z = (unsigned)f2bf(u1.x * sc) | ((unsigned)f2bf(u1.y * sc) << 16);
  pc.w = (unsigned)f2bf(u1.z * sc) | ((unsigned)f2bf(u1.w * sc) << 16);
  pd.x = (unsigned)f2bf(u0.x) | ((unsigned)f2bf(u0.y) << 16);
  pd.y = (unsigned)f2bf(u0.z) | ((unsigned)f2bf(u0.w) << 16);
  pd.z = (unsigned)f2bf(u1.x) | ((unsigned)f2bf(u1.y) << 16);
  pd.w = (unsigned)f2bf(u1.z) | ((unsigned)f2bf(u1.w) << 16);
  *(uint4*)(cn + base + tid * 8) = pc;
  *(uint4*)(catA + (long)row * (2 * D_) + tid * 8) = pd;
}

// sinusoidal posenc [N][D] in bf16
__global__ void prep_pe(ushort* __restrict__ pe) {
  const int id = blockIdx.x * 256 + threadIdx.x;
  const int n = id >> 11, d = id & (D_ - 1);
  const double e = (double)(2 * (d >> 1)) / (double)D_;
  const double rate = exp(e * -9.210340371976184);   // 10000^-e
  const double ang = (double)n * rate;
  const float v = (d & 1) ? (float)cos(ang) : (float)sin(ang);
  pe[id] = f2bf(v);
}

// out[c][r] = bf16(in[r][c]); in is [R][C] fp32
__global__ void transpose_bf16(const float* __restrict__ in, ushort* __restrict__ out,
                               int R, int C) {
  __shared__ float t[32][33];
  const int c0 = blockIdx.x * 32, r0 = blockIdx.y * 32;
  const int tx = threadIdx.x, ty = threadIdx.y;   // (32,8)
  #pragma unroll
  for (int i = 0; i < 32; i += 8) t[ty + i][tx] = in[(long)(r0 + ty + i) * C + c0 + tx];
  __syncthreads();
  #pragma unroll
  for (int i = 0; i < 32; i += 8) out[(long)(c0 + ty + i) * R + r0 + tx] = f2bf(t[tx][ty + i]);
}

// ---------------- NT GEMM: C[m][n] = sum_k A[m][k]*B[n][k]  (m97 structure) ----------------
// LDS k-chunk XOR swizzle: chunk c of row r is stored at slot c ^ ((r>>1)&3), so
// ds_read_b128 fragment reads are bank-conflict-free while global_load_lds stays
// lane-contiguous (we permute which GLOBAL chunk each staging lane fetches).
// MODE 0: sim = relu(acc) -> bf16, atomicAdd row sums into csum
// MODE 1: bf16 store
// MODE 2: softplus(acc + csum[row]*w0[col] + bexp[col]) -> bf16 at col+colOff
// MODE 3: fp32 store
template <int MODE>
__global__ __launch_bounds__(256, 2) void gemm_bt(
    const ushort* __restrict__ Ag, const ushort* __restrict__ Bg, void* __restrict__ Cg,
    int K, long sA, long sB, long sC, int ldc, int colOff,
    float* __restrict__ csum, const float* __restrict__ w0, const float* __restrict__ bexp) {
  __shared__ ushort sAt[BM * BK];   // [row][k-swizzled], 64B rows
  __shared__ ushort sBt[BN * BK];   // [col][k-swizzled]

  const int bz = blockIdx.z;
  const ushort* A  = Ag + (long)bz * sA;
  const ushort* Bp = Bg + (long)bz * sB;

  const int tid = threadIdx.x;
  const int w = tid >> 6, L = tid & 63;
  const int blockRow = blockIdx.x * BM;
  const int blockCol = blockIdx.y * BN;

  // staging: lane L of wave w covers row w*16+L/4 (+64 for round 1),
  // global k-chunk ((L&3) ^ ((L>>3)&3)) so LDS slot order is the swizzled layout
  const int ldRow = w * 16 + (L >> 2);
  const int ldK = (((L & 3) ^ ((L >> 3) & 3)) * 8);
  const ushort* a0 = A  + (long)(blockRow + ldRow) * K + ldK;
  const ushort* a1 = a0 + (long)64 * K;
  const ushort* b0 = Bp + (long)(blockCol + ldRow) * K + ldK;
  const ushort* b1 = b0 + (long)64 * K;
  ushort* sA0 = sAt + w * 512;
  ushort* sA1 = sAt + 2048 + w * 512;
  ushort* sB0 = sBt + w * 512;
  ushort* sB1 = sBt + 2048 + w * 512;

  const int wm = (w & 1) * 64, wn = (w >> 1) * 64;   // wave's 64x64 quadrant
  const int fr = L & 15;                             // fragment row
  const int sw = (((L >> 4) ^ ((fr >> 1) & 3)) * 8); // swizzled k-slot for this lane

  f32x4 acc[4][4] = {};

  for (int k0 = 0; k0 < K; k0 += BK) {
    gld16(sA0, a0); gld16(sA1, a1);
    gld16(sB0, b0); gld16(sB1, b1);
    a0 += BK; a1 += BK; b0 += BK; b1 += BK;
    __syncthreads();                               // staging complete (vmcnt drained)
    bf16x8 af[4], bfv[4];
    #pragma unroll
    for (int i = 0; i < 4; i++) af[i]  = *(const bf16x8*)&sAt[(wm + i * 16 + fr) * BK + sw];
    #pragma unroll
    for (int j = 0; j < 4; j++) bfv[j] = *(const bf16x8*)&sBt[(wn + j * 16 + fr) * BK + sw];
    #pragma unroll
    for (int i = 0; i < 4; i++)
      #pragma unroll
      for (int j = 0; j < 4; j++)
        acc[i][j] = __builtin_amdgcn_mfma_f32_16x16x32_bf16(af[i], bfv[j], acc[i][j], 0, 0, 0);
    __syncthreads();                               // reads done before next-iter overwrite
  }

  const int rq = (L >> 4) * 4;   // C/D: row = rq + reg, col = L&15 (m89-verified)
  const int cq = L & 15;

  if (MODE == 0) {
    ushort* C = (ushort*)Cg + (long)bz * sC;
    float rs[4][4];
    #pragma unroll
    for (int i = 0; i < 4; i++)
      #pragma unroll
      for (int r = 0; r < 4; r++) rs[i][r] = 0.f;
    #pragma unroll
    for (int i = 0; i < 4; i++)
      #pragma unroll
      for (int j = 0; j < 4; j++)
        #pragma unroll
        for (int r = 0; r < 4; r++) {
          const float v = fmaxf(acc[i][j][r], 0.f);
          const int row = blockRow + wm + i * 16 + rq + r;
          const int col = blockCol + wn + j * 16 + cq;
          C[(long)row * ldc + col] = f2bf(v);
          rs[i][r] += v;
        }
    #pragma unroll
    for (int i = 0; i < 4; i++)
      #pragma unroll
      for (int r = 0; r < 4; r++) {
        float s = rs[i][r];
        s += __shfl_xor(s, 1); s += __shfl_xor(s, 2);
        s += __shfl_xor(s, 4); s += __shfl_xor(s, 8);
        if (cq == 0) {
          const int row = blockRow + wm + i * 16 + rq + r;
          atomicAdd(&csum[(long)bz * N_ + row], s);
        }
      }
  } else if (MODE == 1) {
    ushort* C = (ushort*)Cg + (long)bz * sC;
    #pragma unroll
    for (int i = 0; i < 4; i++)
      #pragma unroll
      for (int j = 0; j < 4; j++)
        #pragma unroll
        for (int r = 0; r < 4; r++) {
          const int row = blockRow + wm + i * 16 + rq + r;
          const int col = blockCol + wn + j * 16 + cq;
          C[(long)row * ldc + col] = f2bf(acc[i][j][r]);
        }
  } else if (MODE == 2) {
    ushort* C = (ushort*)Cg + (long)bz * sC;
    #pragma unroll
    for (int i = 0; i < 4; i++)
      #pragma unroll
      for (int j = 0; j < 4; j++)
        #pragma unroll
        for (int r = 0; r < 4; r++) {
          const int row = blockRow + wm + i * 16 + rq + r;
          const int col = blockCol + wn + j * 16 + cq;
          const float x = acc[i][j][r] + csum[(long)bz * N_ + row] * w0[col] + bexp[col];
          const float sp = fmaxf(x, 0.f) + log1pf(expf(-fabsf(x)));
          C[(long)row * ldc + colOff + col] = f2bf(sp);
        }
  } else {
    float* C = (float*)Cg + (long)bz * sC;
    #pragma unroll
    for (int i = 0; i < 4; i++)
      #pragma unroll
      for (int j = 0; j < 4; j++)
        #pragma unroll
        for (int r = 0; r < 4; r++) {
          const int row = blockRow + wm + i * 16 + rq + r;
          const int col = blockCol + wn + j * 16 + cq;
          C[(long)row * ldc + col] = acc[i][j][r];
        }
  }
}

// ---------------- launch ----------------
extern "C" void kernel_launch(void* const* d_in, const int* in_sizes, int n_in,
                              void* d_out, int out_size, void* d_ws, size_t ws_size,
                              hipStream_t stream) {
  const float* data    = (const float*)d_in[0];
  const float* W_exp   = (const float*)d_in[1];
  const float* b_exp   = (const float*)d_in[2];
  const float* W_merge = (const float*)d_in[3];

  char* ws = (char*)d_ws;
  const size_t MB = 1024 * 1024;
  ushort* cnv  = (ushort*)(ws);             // 32MB: cn, then reused as v_out
  ushort* sim  = (ushort*)(ws + 32 * MB);   // 32MB
  ushort* pe   = (ushort*)(ws + 64 * MB);   // 8MB
  ushort* weT  = (ushort*)(ws + 72 * MB);   // 8MB:  W_exp[1:,:]^T
  ushort* wmT  = (ushort*)(ws + 80 * MB);   // 16MB: W_merge^T
  ushort* catA = (ushort*)(ws + 96 * MB);   // 64MB: [data | counter] bf16
  float*  csum = (float*)(ws + 160 * MB);   // 128KB

  hipMemsetAsync(csum, 0, (size_t)B_ * N_ * sizeof(float), stream);
  prep_cn<<<B_ * N_, 256, 0, stream>>>(data, cnv, catA);
  prep_pe<<<(N_ * N_) / 256, 256, 0, stream>>>(pe);
  transpose_bf16<<<dim3(D_ / 32, D_ / 32), dim3(32, 8), 0, stream>>>(W_exp + D_, weT, D_, D_);
  transpose_bf16<<<dim3(D_ / 32, (2 * D_) / 32), dim3(32, 8), 0, stream>>>(W_merge, wmT, 2 * D_, D_);

  dim3 g(N_ / BM, N_ / BN, B_), blk(256);
  // G1: sim = relu(cn cn^T), csum row sums
  gemm_bt<0><<<g, blk, 0, stream>>>(cnv, cnv, sim, D_, (long)N_ * D_, (long)N_ * D_,
                                    (long)N_ * N_, N_, 0, csum, nullptr, nullptr);
  // G2: v_out = pe @ sim  (sim symmetric -> NT form), into cnv region (cn is dead)
  gemm_bt<1><<<g, blk, 0, stream>>>(pe, sim, cnv, N_, 0, (long)N_ * N_,
                                    (long)N_ * N_, N_, 0, nullptr, nullptr, nullptr);
  // G3: catA[:, D:] = softplus(v_out @ W_exp[1:] + csum*w0 + b_exp)
  gemm_bt<2><<<g, blk, 0, stream>>>(cnv, weT, catA, N_, (long)N_ * N_, 0,
                                    (long)N_ * 2 * D_, 2 * D_, D_, csum, W_exp, b_exp);
  // G4: out = catA @ W_merge
  gemm_bt<3><<<g, blk, 0, stream>>>(catA, wmT, d_out, 2 * D_, (long)N_ * 2 * D_, 0,
                                    (long)N_ * D_, D_, 0, nullptr, nullptr, nullptr);
}